// Round 2
// baseline (1218.067 us; speedup 1.0000x reference)
//
#include <hip/hip_runtime.h>
#include <cstddef>

#define NN_ 2048
#define EE_ 512
#define HH_ 8
#define NEG_INF_ -1e9f

// ---------------- mask: bias table + select ----------------
__global__ __launch_bounds__(256) void mask_kernel(const int* __restrict__ D,
    const float* __restrict__ demb, const float* __restrict__ dpw,
    const float* __restrict__ dpb, float* __restrict__ mask) {
  __shared__ float tbl[12];
  int t = threadIdx.x;
  if (t < 12) {
    float s = 0.f;
#pragma unroll
    for (int e = 0; e < 8; e++) s += demb[t * 8 + e] * dpw[e];
    tbl[t] = s + dpb[0];
  }
  __syncthreads();
  size_t idx = (size_t)blockIdx.x * 256 + t;
  int d = D[idx];
  int dc = d < 11 ? d : 11;
  mask[idx] = (d <= 2) ? tbl[dc] : NEG_INF_;
}

// ---------------- layernorm (one block per row) ----------------
__global__ __launch_bounds__(256) void ln_kernel(const float* __restrict__ x,
    const float* __restrict__ scale, const float* __restrict__ bias,
    float* __restrict__ out) {
  int row = blockIdx.x;
  int t = threadIdx.x;
  const float* xr = x + (size_t)row * EE_;
  float a = xr[t], b = xr[t + 256];
  float s = a + b, q = a * a + b * b;
#pragma unroll
  for (int m = 1; m < 64; m <<= 1) {
    s += __shfl_xor(s, m);
    q += __shfl_xor(q, m);
  }
  __shared__ float ps[4], pq[4];
  int w = t >> 6;
  if ((t & 63) == 0) { ps[w] = s; pq[w] = q; }
  __syncthreads();
  s = ps[0] + ps[1] + ps[2] + ps[3];
  q = pq[0] + pq[1] + pq[2] + pq[3];
  float mu = s * (1.f / EE_);
  float var = q * (1.f / EE_) - mu * mu;
  float r = rsqrtf(var + 1e-5f);
  float* orow = out + (size_t)row * EE_;
  orow[t] = (a - mu) * r * scale[t] + bias[t];
  orow[t + 256] = (b - mu) * r * scale[t + 256] + bias[t + 256];
}

// ---------------- fp32 GEMM: C[M,F] = A[M,K] . B[F,K]^T + bias (+relu)(+res) ----
template <int RELU, int RES>
__global__ __launch_bounds__(256) void gemm_nt(const float* __restrict__ A,
    const float* __restrict__ B, const float* __restrict__ bias,
    const float* __restrict__ R, float* __restrict__ C, int M, int F, int K) {
  __shared__ float As[64][17];
  __shared__ float Bs[64][17];
  int bm = blockIdx.y * 64, bf = blockIdx.x * 64;
  int t = threadIdx.x;
  int ty = t >> 4, tx = t & 15;
  int lr = t >> 2, lc = (t & 3) * 4;
  const float* Ap = A + (size_t)(bm + lr) * K + lc;
  const float* Bp = B + (size_t)(bf + lr) * K + lc;
  float acc00 = 0, acc01 = 0, acc02 = 0, acc03 = 0;
  float acc10 = 0, acc11 = 0, acc12 = 0, acc13 = 0;
  float acc20 = 0, acc21 = 0, acc22 = 0, acc23 = 0;
  float acc30 = 0, acc31 = 0, acc32 = 0, acc33 = 0;
  for (int k0 = 0; k0 < K; k0 += 16) {
    float4 av = *(const float4*)(Ap + k0);
    float4 bv = *(const float4*)(Bp + k0);
    As[lr][lc] = av.x; As[lr][lc + 1] = av.y; As[lr][lc + 2] = av.z; As[lr][lc + 3] = av.w;
    Bs[lr][lc] = bv.x; Bs[lr][lc + 1] = bv.y; Bs[lr][lc + 2] = bv.z; Bs[lr][lc + 3] = bv.w;
    __syncthreads();
#pragma unroll
    for (int kk = 0; kk < 16; kk++) {
      float a0 = As[ty * 4 + 0][kk], a1 = As[ty * 4 + 1][kk];
      float a2 = As[ty * 4 + 2][kk], a3 = As[ty * 4 + 3][kk];
      float b0 = Bs[tx * 4 + 0][kk], b1 = Bs[tx * 4 + 1][kk];
      float b2 = Bs[tx * 4 + 2][kk], b3 = Bs[tx * 4 + 3][kk];
      acc00 += a0 * b0; acc01 += a0 * b1; acc02 += a0 * b2; acc03 += a0 * b3;
      acc10 += a1 * b0; acc11 += a1 * b1; acc12 += a1 * b2; acc13 += a1 * b3;
      acc20 += a2 * b0; acc21 += a2 * b1; acc22 += a2 * b2; acc23 += a2 * b3;
      acc30 += a3 * b0; acc31 += a3 * b1; acc32 += a3 * b2; acc33 += a3 * b3;
    }
    __syncthreads();
  }
  float accs[4][4] = {{acc00, acc01, acc02, acc03},
                      {acc10, acc11, acc12, acc13},
                      {acc20, acc21, acc22, acc23},
                      {acc30, acc31, acc32, acc33}};
#pragma unroll
  for (int i = 0; i < 4; i++) {
    int r = bm + ty * 4 + i;
#pragma unroll
    for (int j = 0; j < 4; j++) {
      int c = bf + tx * 4 + j;
      float v = accs[i][j] + bias[c];
      if (RELU) v = fmaxf(v, 0.f);
      if (RES) v += R[(size_t)r * F + c];
      C[(size_t)r * F + c] = v;
    }
  }
}

// ---------------- flash attention: 16 rows x 1 head per block ----------------
__global__ __launch_bounds__(256) void attn_kernel(const float* __restrict__ qkv,
    const float* __restrict__ mask, float* __restrict__ out) {
  int i0 = blockIdx.x * 16;
  int h = blockIdx.y;
  int t = threadIdx.x;
  int ii = t >> 4, dq = t & 15;
  __shared__ float Qs[16][64];
  __shared__ float Ks[64][64];  // XOR-swizzled columns
  __shared__ float Vs[64][64];
  __shared__ float Ps[16][64];
  const float scale = 0.125f;  // 1/sqrt(64)

  for (int idx = t; idx < 16 * 64; idx += 256) {
    int r = idx >> 6, d = idx & 63;
    Qs[r][d] = qkv[(size_t)(i0 + r) * 1536 + h * 64 + d];
  }

  float acc0 = 0, acc1 = 0, acc2 = 0, acc3 = 0;
  float m_run = -INFINITY, l_run = 0.f;
  const float* mrow = mask + (size_t)(i0 + ii) * NN_;
  int swz = (dq & 7) << 2;

  for (int mc = 0; mc < NN_; mc += 64) {
    __syncthreads();  // protect Ks/Vs (prev PV done) and Qs on first iter
    for (int idx = t; idx < 64 * 64; idx += 256) {
      int r = idx >> 6, d = idx & 63;
      int rs = ((r >> 2) & 7) << 2;
      Ks[r][d ^ rs] = qkv[(size_t)(mc + r) * 1536 + EE_ + h * 64 + d];
      Vs[r][d] = qkv[(size_t)(mc + r) * 1536 + 2 * EE_ + h * 64 + d];
    }
    __syncthreads();

    float s0 = 0, s1 = 0, s2 = 0, s3 = 0;
#pragma unroll
    for (int d0 = 0; d0 < 64; d0 += 4) {
      float4 q4 = *(const float4*)&Qs[ii][d0];
      int cs = d0 ^ swz;
      float4 k0 = *(const float4*)&Ks[dq * 4 + 0][cs];
      float4 k1 = *(const float4*)&Ks[dq * 4 + 1][cs];
      float4 k2 = *(const float4*)&Ks[dq * 4 + 2][cs];
      float4 k3 = *(const float4*)&Ks[dq * 4 + 3][cs];
      s0 += q4.x * k0.x + q4.y * k0.y + q4.z * k0.z + q4.w * k0.w;
      s1 += q4.x * k1.x + q4.y * k1.y + q4.z * k1.z + q4.w * k1.w;
      s2 += q4.x * k2.x + q4.y * k2.y + q4.z * k2.z + q4.w * k2.w;
      s3 += q4.x * k3.x + q4.y * k3.y + q4.z * k3.z + q4.w * k3.w;
    }
    s0 = s0 * scale + mrow[mc + dq * 4 + 0];
    s1 = s1 * scale + mrow[mc + dq * 4 + 1];
    s2 = s2 * scale + mrow[mc + dq * 4 + 2];
    s3 = s3 * scale + mrow[mc + dq * 4 + 3];

    float cmax = fmaxf(fmaxf(s0, s1), fmaxf(s2, s3));
#pragma unroll
    for (int m = 1; m < 16; m <<= 1) cmax = fmaxf(cmax, __shfl_xor(cmax, m));
    float m_new = fmaxf(m_run, cmax);
    float fac = __expf(m_run - m_new);  // expf(-inf)=0 on first chunk
    float p0 = __expf(s0 - m_new), p1 = __expf(s1 - m_new);
    float p2 = __expf(s2 - m_new), p3 = __expf(s3 - m_new);
    float ls = p0 + p1 + p2 + p3;
#pragma unroll
    for (int m = 1; m < 16; m <<= 1) ls += __shfl_xor(ls, m);
    l_run = l_run * fac + ls;
    acc0 *= fac; acc1 *= fac; acc2 *= fac; acc3 *= fac;
    m_run = m_new;
    Ps[ii][dq * 4 + 0] = p0;
    Ps[ii][dq * 4 + 1] = p1;
    Ps[ii][dq * 4 + 2] = p2;
    Ps[ii][dq * 4 + 3] = p3;
    __syncthreads();

#pragma unroll 8
    for (int mm = 0; mm < 64; mm++) {
      float p = Ps[ii][mm];
      float4 v4 = *(const float4*)&Vs[mm][dq * 4];
      acc0 += p * v4.x; acc1 += p * v4.y; acc2 += p * v4.z; acc3 += p * v4.w;
    }
  }
  float inv = 1.f / l_run;
  float* orow = out + (size_t)(i0 + ii) * EE_ + h * 64 + dq * 4;
  orow[0] = acc0 * inv; orow[1] = acc1 * inv;
  orow[2] = acc2 * inv; orow[3] = acc3 * inv;
}

// ---------------- final logits + softmax (4 rows per block) ----------------
__global__ __launch_bounds__(256) void logits_kernel(const float* __restrict__ x,
    const float* __restrict__ cw, const float* __restrict__ cb,
    float* __restrict__ out) {
  int t = threadIdx.x;
  int wv = t >> 6, lane = t & 63;
  int row = blockIdx.x * 4 + wv;
  const float* xr = x + (size_t)row * EE_;
  int c = lane >> 2, p = lane & 3;
  const float* w = cw + c * EE_;
  float s = 0.f;
  for (int e = p * 128; e < p * 128 + 128; e++) s += xr[e] * w[e];
  s += __shfl_xor(s, 1);
  s += __shfl_xor(s, 2);
  __shared__ float lg[4][16];
  if (p == 0) lg[wv][c] = s + cb[c];
  __syncthreads();
  if (lane < 16) {
    float mx = -INFINITY;
#pragma unroll
    for (int k = 0; k < 16; k++) mx = fmaxf(mx, lg[wv][k]);
    float sum = 0.f;
#pragma unroll
    for (int k = 0; k < 16; k++) sum += __expf(lg[wv][k] - mx);
    out[(size_t)row * 16 + lane] = __expf(lg[wv][lane] - mx) / sum;
  }
}

// ---------------- driver ----------------
extern "C" void kernel_launch(void* const* d_in, const int* in_sizes, int n_in,
                              void* d_out, int out_size, void* d_ws, size_t ws_size,
                              hipStream_t stream) {
  const int* D = (const int*)d_in[0];
  const float* x = (const float*)d_in[1];
  const float* demb = (const float*)d_in[2];
  const float* dpw = (const float*)d_in[3];
  const float* dpb = (const float*)d_in[4];
  const float* ln1s = (const float*)d_in[5];
  const float* ln1b = (const float*)d_in[6];
  const float* ipw = (const float*)d_in[7];
  const float* ipb = (const float*)d_in[8];
  const float* ow = (const float*)d_in[9];
  const float* ob = (const float*)d_in[10];
  const float* ln2s = (const float*)d_in[11];
  const float* ln2b = (const float*)d_in[12];
  const float* f1w = (const float*)d_in[13];
  const float* f1b = (const float*)d_in[14];
  const float* f2w = (const float*)d_in[15];
  const float* f2b = (const float*)d_in[16];
  const float* cw = (const float*)d_in[17];
  const float* cb = (const float*)d_in[18];

  const size_t NNe = (size_t)NN_ * NN_;     // 4M
  const size_t NEe = (size_t)NN_ * EE_;     // 1M
  float* ws = (float*)d_ws;
  float* mask = ws;                 // 4M floats
  float* xbuf = mask + NNe;         // 1M
  float* xn = xbuf + NEe;           // 1M
  float* qkv = xn + NEe;            // 3M
  float* attn = qkv + 3 * NEe;      // 1M
  float* hbuf = attn + NEe;         // 2M

  hipMemcpyAsync(xbuf, x, NEe * sizeof(float), hipMemcpyDeviceToDevice, stream);
  mask_kernel<<<NNe / 256, 256, 0, stream>>>(D, demb, dpw, dpb, mask);

  for (int l = 0; l < 2; l++) {
    ln_kernel<<<NN_, 256, 0, stream>>>(xbuf, ln1s + l * EE_, ln1b + l * EE_, xn);
    gemm_nt<0, 0><<<dim3(24, 32), 256, 0, stream>>>(
        xn, ipw + (size_t)l * 3 * EE_ * EE_, ipb + l * 3 * EE_, nullptr, qkv,
        NN_, 3 * EE_, EE_);
    attn_kernel<<<dim3(NN_ / 16, HH_), 256, 0, stream>>>(qkv, mask, attn);
    gemm_nt<0, 1><<<dim3(8, 32), 256, 0, stream>>>(
        attn, ow + (size_t)l * EE_ * EE_, ob + l * EE_, xbuf, xbuf,
        NN_, EE_, EE_);
    ln_kernel<<<NN_, 256, 0, stream>>>(xbuf, ln2s + l * EE_, ln2b + l * EE_, xn);
    gemm_nt<1, 0><<<dim3(16, 32), 256, 0, stream>>>(
        xn, f1w + (size_t)l * 2 * EE_ * EE_, f1b + l * 2 * EE_, nullptr, hbuf,
        NN_, 2 * EE_, EE_);
    gemm_nt<0, 1><<<dim3(8, 32), 256, 0, stream>>>(
        hbuf, f2w + (size_t)l * EE_ * 2 * EE_, f2b + l * EE_, xbuf, xbuf,
        NN_, EE_, 2 * EE_);
  }
  logits_kernel<<<NN_ / 4, 256, 0, stream>>>(xbuf, cw, cb, (float*)d_out);
}

// Round 3
// 407.892 us; speedup vs baseline: 2.9863x; 2.9863x over previous
//
#include <hip/hip_runtime.h>
#include <cstddef>
#include <cstdint>

#define NN 2048
#define EE 512
#define HH 8
#define QKVF 1536

typedef __attribute__((ext_vector_type(4))) float f32x4;
typedef __attribute__((ext_vector_type(8))) short s16x8;
typedef __attribute__((ext_vector_type(4))) short s16x4;

static __device__ __forceinline__ unsigned short f2bf(float x) {
  union { float f; unsigned int u; } c; c.f = x;
  unsigned int r = (c.u + 0x7FFFu + ((c.u >> 16) & 1u)) >> 16;
  return (unsigned short)r;
}
static __device__ __forceinline__ float bf2f(unsigned short b) {
  union { unsigned int u; float f; } c; c.u = ((unsigned int)b) << 16;
  return c.f;
}

#define GLL16(gp, lp) __builtin_amdgcn_global_load_lds( \
    (const __attribute__((address_space(1))) void*)(gp), \
    (__attribute__((address_space(3))) void*)(lp), 16, 0, 0)

// ---------------- weight fp32 -> bf16 ----------------
__global__ __launch_bounds__(256) void cvt_bf4(const float* __restrict__ src,
    unsigned short* __restrict__ dst, int n4) {
  int i = blockIdx.x * 256 + threadIdx.x;
  if (i < n4) {
    float4 v = ((const float4*)src)[i];
    s16x4 o;
    o[0] = (short)f2bf(v.x); o[1] = (short)f2bf(v.y);
    o[2] = (short)f2bf(v.z); o[3] = (short)f2bf(v.w);
    ((s16x4*)dst)[i] = o;
  }
}

// ---------------- wtbl: exp(bias_d) for d=0,1,2; 0 for masked ----------------
__global__ void wtbl_kernel(const float* __restrict__ demb, const float* __restrict__ dpw,
    const float* __restrict__ dpb, float* __restrict__ wtbl) {
  int t = threadIdx.x;
  if (t < 4) {
    float v = 0.f;
    if (t < 3) {
      float s = 0.f;
      for (int e = 0; e < 8; e++) s += demb[t * 8 + e] * dpw[e];
      v = expf(s + dpb[0]);
    }
    wtbl[t] = v;
  }
}

// ---------------- packed distance codes: u32 = codes for kv {c,c+16,c+32,c+48} ---
__global__ __launch_bounds__(256) void mask_pack(const int* __restrict__ D,
    unsigned int* __restrict__ codes) {
  int id = blockIdx.x * 256 + threadIdx.x;  // 2048*512 total
  int row = id >> 9;
  int u = id & 511;
  int ch = u >> 4, col = u & 15;
  int base = ch * 64 + col;
  unsigned int pk = 0;
#pragma unroll
  for (int i = 0; i < 4; i++) {
    int d = D[(size_t)row * NN + base + 16 * i];
    unsigned int c = (d <= 2) ? (unsigned int)d : 3u;
    pk |= c << (8 * i);
  }
  codes[id] = pk;
}

// ---------------- layernorm fp32 in -> bf16 out ----------------
__global__ __launch_bounds__(256) void ln_kernel(const float* __restrict__ x,
    const float* __restrict__ scale, const float* __restrict__ bias,
    unsigned short* __restrict__ out) {
  int row = blockIdx.x;
  int t = threadIdx.x;
  const float* xr = x + (size_t)row * EE;
  float a = xr[t], b = xr[t + 256];
  float s = a + b, q = a * a + b * b;
#pragma unroll
  for (int m = 1; m < 64; m <<= 1) {
    s += __shfl_xor(s, m);
    q += __shfl_xor(q, m);
  }
  __shared__ float ps[4], pq[4];
  int w = t >> 6;
  if ((t & 63) == 0) { ps[w] = s; pq[w] = q; }
  __syncthreads();
  s = ps[0] + ps[1] + ps[2] + ps[3];
  q = pq[0] + pq[1] + pq[2] + pq[3];
  float mu = s * (1.f / EE);
  float var = q * (1.f / EE) - mu * mu;
  float r = rsqrtf(var + 1e-5f);
  unsigned short* orow = out + (size_t)row * EE;
  orow[t] = f2bf((a - mu) * r * scale[t] + bias[t]);
  orow[t + 256] = f2bf((b - mu) * r * scale[t + 256] + bias[t + 256]);
}

// ---------------- bf16 MFMA GEMM: C[M,F] = A[M,K].B[F,K]^T + bias ----------------
template <int RELU, int RES, int OBF>
__global__ __launch_bounds__(256) void gemm_bf(
    const unsigned short* __restrict__ A, const unsigned short* __restrict__ B,
    const float* __restrict__ bias, const float* __restrict__ R,
    void* __restrict__ Cout, int M, int F, int K) {
  __shared__ __attribute__((aligned(16))) unsigned short Al[64 * 64];
  __shared__ __attribute__((aligned(16))) unsigned short Bl[64 * 64];
  const int t = threadIdx.x;
  const int w = t >> 6, l = t & 63;
  const int fr = l & 15, fs = l >> 4;
  const int wr = w >> 1, wc = w & 1;
  const int bm = blockIdx.y * 64, bf = blockIdx.x * 64;
  const int srow = l >> 3, slot = l & 7;
  f32x4 acc[2][2];
  f32x4 zero = {0.f, 0.f, 0.f, 0.f};
#pragma unroll
  for (int i = 0; i < 2; i++)
#pragma unroll
    for (int j = 0; j < 2; j++) acc[i][j] = zero;

  for (int k0 = 0; k0 < K; k0 += 64) {
    __syncthreads();
#pragma unroll
    for (int rnd = 0; rnd < 2; rnd++) {
      int rowblk = w + 4 * rnd;            // 0..7
      int row = rowblk * 8 + srow;         // 0..63
      int koff = (slot * 8) ^ ((row & 7) * 8);
      GLL16(A + (size_t)(bm + row) * K + k0 + koff, Al + rowblk * 512);
      GLL16(B + (size_t)(bf + row) * K + k0 + koff, Bl + rowblk * 512);
    }
    __syncthreads();
    s16x8 af[2][2], bg[2][2];
#pragma unroll
    for (int mi = 0; mi < 2; mi++)
#pragma unroll
      for (int ks = 0; ks < 2; ks++) {
        int row = 32 * wr + 16 * mi + fr;
        af[mi][ks] = *(const s16x8*)&Al[row * 64 + ((ks * 32 + fs * 8) ^ ((row & 7) * 8))];
      }
#pragma unroll
    for (int ni = 0; ni < 2; ni++)
#pragma unroll
      for (int ks = 0; ks < 2; ks++) {
        int row = 32 * wc + 16 * ni + fr;
        bg[ni][ks] = *(const s16x8*)&Bl[row * 64 + ((ks * 32 + fs * 8) ^ ((row & 7) * 8))];
      }
#pragma unroll
    for (int mi = 0; mi < 2; mi++)
#pragma unroll
      for (int ni = 0; ni < 2; ni++)
#pragma unroll
        for (int ks = 0; ks < 2; ks++)
          acc[mi][ni] = __builtin_amdgcn_mfma_f32_16x16x32_bf16(
              af[mi][ks], bg[ni][ks], acc[mi][ni], 0, 0, 0);
  }
#pragma unroll
  for (int mi = 0; mi < 2; mi++)
#pragma unroll
    for (int ni = 0; ni < 2; ni++) {
      int gcol = bf + 32 * wc + 16 * ni + fr;
      float bb = bias[gcol];
#pragma unroll
      for (int r = 0; r < 4; r++) {
        int grow = bm + 32 * wr + 16 * mi + fs * 4 + r;
        float v = acc[mi][ni][r] + bb;
        if (RELU) v = fmaxf(v, 0.f);
        if (RES) v += R[(size_t)grow * F + gcol];
        if (OBF) ((unsigned short*)Cout)[(size_t)grow * F + gcol] = f2bf(v);
        else ((float*)Cout)[(size_t)grow * F + gcol] = v;
      }
    }
}

// ---------------- MFMA flash attention: 64 q-rows x 1 head per block ----------------
__global__ __launch_bounds__(256) void attn_mfma(
    const unsigned short* __restrict__ qkv, const unsigned int* __restrict__ codes,
    const float* __restrict__ wtbl, unsigned short* __restrict__ attn_out) {
  __shared__ __attribute__((aligned(16))) unsigned short Kl[64 * 64];
  __shared__ __attribute__((aligned(16))) unsigned short Vt[64 * 64];
  __shared__ __attribute__((aligned(16))) unsigned short Pl[4][16 * 64];
  const int t = threadIdx.x;
  const int w = t >> 6, l = t & 63;
  const int fr = l & 15, fs = l >> 4;
  const int h = blockIdx.y;
  const int qrow0 = blockIdx.x * 64 + w * 16;

  s16x8 qf[2];
#pragma unroll
  for (int ks = 0; ks < 2; ks++)
    qf[ks] = *(const s16x8*)&qkv[(size_t)(qrow0 + fr) * QKVF + h * 64 + ks * 32 + fs * 8];

  const float w0 = wtbl[0], w1 = wtbl[1], w2 = wtbl[2];

  f32x4 o[4];
  float m_run[4], l_run[4];
  f32x4 zero = {0.f, 0.f, 0.f, 0.f};
#pragma unroll
  for (int i = 0; i < 4; i++) { o[i] = zero; m_run[i] = -INFINITY; l_run[i] = 0.f; }

  const int krow = t >> 2, kc = (t & 3) * 16;
  const int vkv = (t & 15) * 4, vd = (t >> 4) * 4;
  const unsigned short* kbase = qkv + EE + h * 64;
  const unsigned short* vbase = qkv + 2 * EE + h * 64;
  s16x8 kreg[2];
  s16x4 vreg[4];
#pragma unroll
  for (int i = 0; i < 2; i++)
    kreg[i] = *(const s16x8*)&kbase[(size_t)krow * QKVF + kc + i * 8];
#pragma unroll
  for (int i = 0; i < 4; i++)
    vreg[i] = *(const s16x4*)&vbase[(size_t)(vkv + i) * QKVF + vd];

  for (int ch = 0; ch < NN / 64; ch++) {
    __syncthreads();   // previous chunk's LDS reads done
#pragma unroll
    for (int i = 0; i < 2; i++)
      *(s16x8*)&Kl[krow * 64 + ((kc + i * 8) ^ ((krow & 7) * 8))] = kreg[i];
#pragma unroll
    for (int dj = 0; dj < 4; dj++) {
      int d = vd + dj;
      s16x4 pk;
      pk[0] = vreg[0][dj]; pk[1] = vreg[1][dj]; pk[2] = vreg[2][dj]; pk[3] = vreg[3][dj];
      *(s16x4*)&Vt[d * 64 + (vkv ^ ((d & 7) * 8))] = pk;
    }
    __syncthreads();   // staging visible
    if (ch + 1 < NN / 64) {  // prefetch next chunk into regs (latency hides under compute)
      int kv0 = (ch + 1) * 64;
#pragma unroll
      for (int i = 0; i < 2; i++)
        kreg[i] = *(const s16x8*)&kbase[(size_t)(kv0 + krow) * QKVF + kc + i * 8];
#pragma unroll
      for (int i = 0; i < 4; i++)
        vreg[i] = *(const s16x4*)&vbase[(size_t)(kv0 + vkv + i) * QKVF + vd];
    }
    unsigned int cd[4];
#pragma unroll
    for (int r = 0; r < 4; r++)
      cd[r] = codes[(size_t)(qrow0 + fs * 4 + r) * (NN / 4) + ch * 16 + fr];

    // QK^T
    f32x4 s[4];
#pragma unroll
    for (int ni = 0; ni < 4; ni++) s[ni] = zero;
#pragma unroll
    for (int ni = 0; ni < 4; ni++) {
      int row = 16 * ni + fr;
#pragma unroll
      for (int ks = 0; ks < 2; ks++) {
        s16x8 kf = *(const s16x8*)&Kl[row * 64 + ((ks * 32 + fs * 8) ^ ((row & 7) * 8))];
        s[ni] = __builtin_amdgcn_mfma_f32_16x16x32_bf16(qf[ks], kf, s[ni], 0, 0, 0);
      }
    }
    // online softmax, p = exp(s*scale - m) * w[code]
#pragma unroll
    for (int r = 0; r < 4; r++) {
      float a = fmaxf(fmaxf(s[0][r], s[1][r]), fmaxf(s[2][r], s[3][r]));
#pragma unroll
      for (int m = 1; m < 16; m <<= 1) a = fmaxf(a, __shfl_xor(a, m));
      float cmax = a * 0.125f;
      float mnew = fmaxf(m_run[r], cmax);
      float fac = __expf(m_run[r] - mnew);
      m_run[r] = mnew;
#pragma unroll
      for (int dn = 0; dn < 4; dn++) o[dn][r] *= fac;
      int prow = fs * 4 + r;
      float psum = 0.f;
#pragma unroll
      for (int ni = 0; ni < 4; ni++) {
        unsigned int code = (cd[r] >> (8 * ni)) & 255u;
        float wsel = code == 0u ? w0 : (code == 1u ? w1 : (code == 2u ? w2 : 0.f));
        float p = __expf(s[ni][r] * 0.125f - mnew) * wsel;
        unsigned short pb = f2bf(p);
        psum += bf2f(pb);   // l sums exactly what PV uses
        Pl[w][prow * 64 + ((16 * ni + fr) ^ ((prow & 7) * 8))] = pb;
      }
#pragma unroll
      for (int m = 1; m < 16; m <<= 1) psum += __shfl_xor(psum, m);
      l_run[r] = l_run[r] * fac + psum;
    }
    // PV
#pragma unroll
    for (int ks = 0; ks < 2; ks++) {
      s16x8 pa = *(const s16x8*)&Pl[w][fr * 64 + ((ks * 32 + fs * 8) ^ ((fr & 7) * 8))];
#pragma unroll
      for (int dn = 0; dn < 4; dn++) {
        int row = 16 * dn + fr;
        s16x8 vf = *(const s16x8*)&Vt[row * 64 + ((ks * 32 + fs * 8) ^ ((row & 7) * 8))];
        o[dn] = __builtin_amdgcn_mfma_f32_16x16x32_bf16(pa, vf, o[dn], 0, 0, 0);
      }
    }
  }
#pragma unroll
  for (int r = 0; r < 4; r++) {
    float inv = 1.f / l_run[r];
    int row = qrow0 + fs * 4 + r;
#pragma unroll
    for (int dn = 0; dn < 4; dn++)
      attn_out[(size_t)row * EE + h * 64 + 16 * dn + fr] = f2bf(o[dn][r] * inv);
  }
}

// ---------------- final logits + softmax (4 rows per block, fp32) ----------------
__global__ __launch_bounds__(256) void logits_kernel(const float* __restrict__ x,
    const float* __restrict__ cw, const float* __restrict__ cb,
    float* __restrict__ out) {
  int t = threadIdx.x;
  int wv = t >> 6, lane = t & 63;
  int row = blockIdx.x * 4 + wv;
  const float* xr = x + (size_t)row * EE;
  int c = lane >> 2, p = lane & 3;
  const float* w = cw + c * EE;
  float s = 0.f;
  for (int e = p * 128; e < p * 128 + 128; e++) s += xr[e] * w[e];
  s += __shfl_xor(s, 1);
  s += __shfl_xor(s, 2);
  __shared__ float lg[4][16];
  if (p == 0) lg[wv][c] = s + cb[c];
  __syncthreads();
  if (lane < 16) {
    float mx = -INFINITY;
#pragma unroll
    for (int k = 0; k < 16; k++) mx = fmaxf(mx, lg[wv][k]);
    float sum = 0.f;
#pragma unroll
    for (int k = 0; k < 16; k++) sum += __expf(lg[wv][k] - mx);
    out[(size_t)row * 16 + lane] = __expf(lg[wv][lane] - mx) / sum;
  }
}

// ---------------- driver ----------------
extern "C" void kernel_launch(void* const* d_in, const int* in_sizes, int n_in,
                              void* d_out, int out_size, void* d_ws, size_t ws_size,
                              hipStream_t stream) {
  const int* D = (const int*)d_in[0];
  const float* x = (const float*)d_in[1];
  const float* demb = (const float*)d_in[2];
  const float* dpw = (const float*)d_in[3];
  const float* dpb = (const float*)d_in[4];
  const float* ln1s = (const float*)d_in[5];
  const float* ln1b = (const float*)d_in[6];
  const float* ipw = (const float*)d_in[7];
  const float* ipb = (const float*)d_in[8];
  const float* ow = (const float*)d_in[9];
  const float* ob = (const float*)d_in[10];
  const float* ln2s = (const float*)d_in[11];
  const float* ln2b = (const float*)d_in[12];
  const float* f1w = (const float*)d_in[13];
  const float* f1b = (const float*)d_in[14];
  const float* f2w = (const float*)d_in[15];
  const float* f2b = (const float*)d_in[16];
  const float* cw = (const float*)d_in[17];
  const float* cb = (const float*)d_in[18];

  char* base = (char*)d_ws;
  unsigned int* codes = (unsigned int*)base;                        // 4 MB
  float* xbuf = (float*)(base + (4u << 20));                        // 4 MB
  unsigned short* qkv = (unsigned short*)(base + (8u << 20));       // 6 MB
  unsigned short* xn = (unsigned short*)(base + (14u << 20));       // 2 MB
  unsigned short* attnb = (unsigned short*)(base + (16u << 20));    // 2 MB
  unsigned short* hbuf = (unsigned short*)(base + (18u << 20));     // 4 MB
  unsigned short* ipw_bf = (unsigned short*)(base + (22u << 20));   // 3 MB
  unsigned short* ow_bf = (unsigned short*)(base + (25u << 20));    // 1 MB
  unsigned short* f1w_bf = (unsigned short*)(base + (26u << 20));   // 2 MB
  unsigned short* f2w_bf = (unsigned short*)(base + (28u << 20));   // 2 MB
  float* wtbl = (float*)(base + (30u << 20));

  cvt_bf4<<<(393216 + 255) / 256, 256, 0, stream>>>(ipw, ipw_bf, 393216);
  cvt_bf4<<<(131072 + 255) / 256, 256, 0, stream>>>(ow, ow_bf, 131072);
  cvt_bf4<<<(262144 + 255) / 256, 256, 0, stream>>>(f1w, f1w_bf, 262144);
  cvt_bf4<<<(262144 + 255) / 256, 256, 0, stream>>>(f2w, f2w_bf, 262144);
  wtbl_kernel<<<1, 64, 0, stream>>>(demb, dpw, dpb, wtbl);
  mask_pack<<<4096, 256, 0, stream>>>(D, codes);
  hipMemcpyAsync(xbuf, x, (size_t)NN * EE * sizeof(float), hipMemcpyDeviceToDevice, stream);

  for (int l = 0; l < 2; l++) {
    ln_kernel<<<NN, 256, 0, stream>>>(xbuf, ln1s + l * EE, ln1b + l * EE, xn);
    gemm_bf<0, 0, 1><<<dim3(24, 32), 256, 0, stream>>>(
        xn, ipw_bf + (size_t)l * 786432, ipb + l * 1536, nullptr, qkv, NN, 1536, 512);
    attn_mfma<<<dim3(32, 8), 256, 0, stream>>>(qkv, codes, wtbl, attnb);
    gemm_bf<0, 1, 0><<<dim3(8, 32), 256, 0, stream>>>(
        attnb, ow_bf + (size_t)l * 262144, ob + l * EE, xbuf, xbuf, NN, 512, 512);
    ln_kernel<<<NN, 256, 0, stream>>>(xbuf, ln2s + l * EE, ln2b + l * EE, xn);
    gemm_bf<1, 0, 1><<<dim3(16, 32), 256, 0, stream>>>(
        xn, f1w_bf + (size_t)l * 524288, f1b + l * 1024, nullptr, hbuf, NN, 1024, 512);
    gemm_bf<0, 1, 0><<<dim3(8, 32), 256, 0, stream>>>(
        hbuf, f2w_bf + (size_t)l * 524288, f2b + l * EE, xbuf, xbuf, NN, 512, 1024);
  }
  logits_kernel<<<NN / 4, 256, 0, stream>>>(xbuf, cw, cb, (float*)d_out);
}

// Round 6
// 324.364 us; speedup vs baseline: 3.7552x; 1.2575x over previous
//
#include <hip/hip_runtime.h>
#include <cstddef>
#include <cstdint>

#define NN 2048
#define EE 512
#define HH 8
#define QKVF 1536
#define NSEG 4

typedef __attribute__((ext_vector_type(4))) float f32x4;
typedef __attribute__((ext_vector_type(8))) short s16x8;
typedef __attribute__((ext_vector_type(4))) short s16x4;

static __device__ __forceinline__ unsigned short f2bf(float x) {
  union { float f; unsigned int u; } c; c.f = x;
  unsigned int r = (c.u + 0x7FFFu + ((c.u >> 16) & 1u)) >> 16;
  return (unsigned short)r;
}
static __device__ __forceinline__ float bf2f(unsigned short b) {
  union { unsigned int u; float f; } c; c.u = ((unsigned int)b) << 16;
  return c.f;
}

#define GLL16(gp, lp) __builtin_amdgcn_global_load_lds( \
    (const __attribute__((address_space(1))) void*)(gp), \
    (__attribute__((address_space(3))) void*)(lp), 16, 0, 0)

// ---------------- weight fp32 -> bf16 ----------------
__global__ __launch_bounds__(256) void cvt_bf4(const float* __restrict__ src,
    unsigned short* __restrict__ dst, int n4) {
  int i = blockIdx.x * 256 + threadIdx.x;
  if (i < n4) {
    float4 v = ((const float4*)src)[i];
    s16x4 o;
    o[0] = (short)f2bf(v.x); o[1] = (short)f2bf(v.y);
    o[2] = (short)f2bf(v.z); o[3] = (short)f2bf(v.w);
    ((s16x4*)dst)[i] = o;
  }
}

// ---------------- wtbl: exp(bias_d) for d=0,1,2; 0 for masked ----------------
__global__ void wtbl_kernel(const float* __restrict__ demb, const float* __restrict__ dpw,
    const float* __restrict__ dpb, float* __restrict__ wtbl) {
  int t = threadIdx.x;
  if (t < 4) {
    float v = 0.f;
    if (t < 3) {
      float s = 0.f;
      for (int e = 0; e < 8; e++) s += demb[t * 8 + e] * dpw[e];
      v = expf(s + dpb[0]);
    }
    wtbl[t] = v;
  }
}

// ---------------- packed distance codes: u32 = codes for kv {c,c+16,c+32,c+48} ---
__global__ __launch_bounds__(256) void mask_pack(const int* __restrict__ D,
    unsigned int* __restrict__ codes) {
  int id = blockIdx.x * 256 + threadIdx.x;  // 2048*512 total
  int row = id >> 9;
  int u = id & 511;
  int ch = u >> 4, col = u & 15;
  int base = ch * 64 + col;
  unsigned int pk = 0;
#pragma unroll
  for (int i = 0; i < 4; i++) {
    int d = D[(size_t)row * NN + base + 16 * i];
    unsigned int c = (d <= 2) ? (unsigned int)d : 3u;
    pk |= c << (8 * i);
  }
  codes[id] = pk;
}

// ---------------- layernorm fp32 in -> bf16 out ----------------
__global__ __launch_bounds__(256) void ln_kernel(const float* __restrict__ x,
    const float* __restrict__ scale, const float* __restrict__ bias,
    unsigned short* __restrict__ out) {
  int row = blockIdx.x;
  int t = threadIdx.x;
  const float* xr = x + (size_t)row * EE;
  float a = xr[t], b = xr[t + 256];
  float s = a + b, q = a * a + b * b;
#pragma unroll
  for (int m = 1; m < 64; m <<= 1) {
    s += __shfl_xor(s, m);
    q += __shfl_xor(q, m);
  }
  __shared__ float ps[4], pq[4];
  int w = t >> 6;
  if ((t & 63) == 0) { ps[w] = s; pq[w] = q; }
  __syncthreads();
  s = ps[0] + ps[1] + ps[2] + ps[3];
  q = pq[0] + pq[1] + pq[2] + pq[3];
  float mu = s * (1.f / EE);
  float var = q * (1.f / EE) - mu * mu;
  float r = rsqrtf(var + 1e-5f);
  unsigned short* orow = out + (size_t)row * EE;
  orow[t] = f2bf((a - mu) * r * scale[t] + bias[t]);
  orow[t + 256] = f2bf((b - mu) * r * scale[t + 256] + bias[t + 256]);
}

// ------- bf16 MFMA GEMM, 128x64 tile: C[M,F] = A[M,K].B[F,K]^T + bias --------
template <int RELU, int RES, int OBF>
__global__ __launch_bounds__(256) void gemm_bf(
    const unsigned short* __restrict__ A, const unsigned short* __restrict__ B,
    const float* __restrict__ bias, const float* __restrict__ R,
    void* __restrict__ Cout, int M, int F, int K) {
  __shared__ __attribute__((aligned(16))) unsigned short Al[128 * 64];  // 16 KB
  __shared__ __attribute__((aligned(16))) unsigned short Bl[64 * 64];   //  8 KB
  const int t = threadIdx.x;
  const int w = t >> 6, l = t & 63;
  const int fr = l & 15, fs = l >> 4;
  const int bm = blockIdx.y * 128, bf = blockIdx.x * 64;
  const int srow = l >> 3, slot = l & 7;
  f32x4 acc[2][4];
  f32x4 zero = {0.f, 0.f, 0.f, 0.f};
#pragma unroll
  for (int i = 0; i < 2; i++)
#pragma unroll
    for (int j = 0; j < 4; j++) acc[i][j] = zero;

  for (int k0 = 0; k0 < K; k0 += 64) {
    __syncthreads();
#pragma unroll
    for (int rnd = 0; rnd < 4; rnd++) {          // A: 128 rows
      int rowblk = w * 4 + rnd;                  // 0..15
      int row = rowblk * 8 + srow;               // 0..127
      int koff = (slot * 8) ^ ((row & 7) * 8);
      GLL16(A + (size_t)(bm + row) * K + k0 + koff, Al + rowblk * 512);
    }
#pragma unroll
    for (int rnd = 0; rnd < 2; rnd++) {          // B: 64 rows
      int rowblk = w * 2 + rnd;                  // 0..7
      int row = rowblk * 8 + srow;
      int koff = (slot * 8) ^ ((row & 7) * 8);
      GLL16(B + (size_t)(bf + row) * K + k0 + koff, Bl + rowblk * 512);
    }
    __syncthreads();
    s16x8 af[2][2], bg[4][2];
#pragma unroll
    for (int mi = 0; mi < 2; mi++)
#pragma unroll
      for (int ks = 0; ks < 2; ks++) {
        int row = w * 32 + 16 * mi + fr;
        af[mi][ks] = *(const s16x8*)&Al[row * 64 + ((ks * 32 + fs * 8) ^ ((row & 7) * 8))];
      }
#pragma unroll
    for (int ni = 0; ni < 4; ni++)
#pragma unroll
      for (int ks = 0; ks < 2; ks++) {
        int row = 16 * ni + fr;
        bg[ni][ks] = *(const s16x8*)&Bl[row * 64 + ((ks * 32 + fs * 8) ^ ((row & 7) * 8))];
      }
#pragma unroll
    for (int mi = 0; mi < 2; mi++)
#pragma unroll
      for (int ni = 0; ni < 4; ni++)
#pragma unroll
        for (int ks = 0; ks < 2; ks++)
          acc[mi][ni] = __builtin_amdgcn_mfma_f32_16x16x32_bf16(
              af[mi][ks], bg[ni][ks], acc[mi][ni], 0, 0, 0);
  }
#pragma unroll
  for (int mi = 0; mi < 2; mi++)
#pragma unroll
    for (int ni = 0; ni < 4; ni++) {
      int gcol = bf + 16 * ni + fr;
      float bb = bias[gcol];
#pragma unroll
      for (int r = 0; r < 4; r++) {
        int grow = bm + w * 32 + 16 * mi + fs * 4 + r;
        float v = acc[mi][ni][r] + bb;
        if (RELU) v = fmaxf(v, 0.f);
        if (RES) v += R[(size_t)grow * F + gcol];
        if (OBF) ((unsigned short*)Cout)[(size_t)grow * F + gcol] = f2bf(v);
        else ((float*)Cout)[(size_t)grow * F + gcol] = v;
      }
    }
}

// -------- MFMA flash attention, split-KV: 64 q x 1 head x 512 kv per block ------
__global__ __launch_bounds__(256) void attn_mfma(
    const unsigned short* __restrict__ qkv, const unsigned int* __restrict__ codes,
    const float* __restrict__ wtbl, float* __restrict__ po, float* __restrict__ lpart) {
  __shared__ __attribute__((aligned(16))) unsigned short Kl[64 * 64];
  __shared__ __attribute__((aligned(16))) unsigned short Vt[64 * 64];
  __shared__ __attribute__((aligned(16))) unsigned short Pl[4][16 * 64];
  const int t = threadIdx.x;
  const int w = t >> 6, l = t & 63;
  const int fr = l & 15, fs = l >> 4;
  const int h = blockIdx.y;
  const int seg = blockIdx.z;
  const int qrow0 = blockIdx.x * 64 + w * 16;
  const int kvbase = seg * (NN / NSEG);
  const float C2 = 0.18033688011112042f;  // 0.125 * log2(e)

  s16x8 qf[2];
#pragma unroll
  for (int ks = 0; ks < 2; ks++)
    qf[ks] = *(const s16x8*)&qkv[(size_t)(qrow0 + fr) * QKVF + h * 64 + ks * 32 + fs * 8];

  const float w0 = wtbl[0], w1 = wtbl[1], w2 = wtbl[2];

  f32x4 o[4];
  float lacc[4];
  f32x4 zero = {0.f, 0.f, 0.f, 0.f};
#pragma unroll
  for (int i = 0; i < 4; i++) { o[i] = zero; lacc[i] = 0.f; }

  const int krow = t >> 2, kc = (t & 3) * 16;
  const int vkv = (t & 15) * 4, vd = (t >> 4) * 4;
  const unsigned short* kbase = qkv + EE + h * 64;
  const unsigned short* vbase = qkv + 2 * EE + h * 64;
  s16x8 kreg[2];
  s16x4 vreg[4];
#pragma unroll
  for (int i = 0; i < 2; i++)
    kreg[i] = *(const s16x8*)&kbase[(size_t)(kvbase + krow) * QKVF + kc + i * 8];
#pragma unroll
  for (int i = 0; i < 4; i++)
    vreg[i] = *(const s16x4*)&vbase[(size_t)(kvbase + vkv + i) * QKVF + vd];

  for (int ch = 0; ch < NN / NSEG / 64; ch++) {
    __syncthreads();   // previous chunk's LDS reads done
#pragma unroll
    for (int i = 0; i < 2; i++)
      *(s16x8*)&Kl[krow * 64 + ((kc + i * 8) ^ ((krow & 7) * 8))] = kreg[i];
#pragma unroll
    for (int dj = 0; dj < 4; dj++) {
      int d = vd + dj;
      s16x4 pk;
      pk[0] = vreg[0][dj]; pk[1] = vreg[1][dj]; pk[2] = vreg[2][dj]; pk[3] = vreg[3][dj];
      *(s16x4*)&Vt[d * 64 + (vkv ^ ((d & 7) * 8))] = pk;
    }
    __syncthreads();   // staging visible
    if (ch + 1 < NN / NSEG / 64) {
      int kv0 = kvbase + (ch + 1) * 64;
#pragma unroll
      for (int i = 0; i < 2; i++)
        kreg[i] = *(const s16x8*)&kbase[(size_t)(kv0 + krow) * QKVF + kc + i * 8];
#pragma unroll
      for (int i = 0; i < 4; i++)
        vreg[i] = *(const s16x4*)&vbase[(size_t)(kv0 + vkv + i) * QKVF + vd];
    }
    int gc = kvbase / 64 + ch;
    unsigned int cd[4];
#pragma unroll
    for (int r = 0; r < 4; r++)
      cd[r] = codes[(size_t)(qrow0 + fs * 4 + r) * (NN / 4) + gc * 16 + fr];

    // QK^T
    f32x4 s[4];
#pragma unroll
    for (int ni = 0; ni < 4; ni++) s[ni] = zero;
#pragma unroll
    for (int ni = 0; ni < 4; ni++) {
      int row = 16 * ni + fr;
#pragma unroll
      for (int ks = 0; ks < 2; ks++) {
        s16x8 kf = *(const s16x8*)&Kl[row * 64 + ((ks * 32 + fs * 8) ^ ((row & 7) * 8))];
        s[ni] = __builtin_amdgcn_mfma_f32_16x16x32_bf16(qf[ks], kf, s[ni], 0, 0, 0);
      }
    }
    // softmax numerator, fixed reference point (m = 0): p = 2^(s*C2) * w[code]
#pragma unroll
    for (int r = 0; r < 4; r++) {
      int prow = fs * 4 + r;
      float psum = 0.f;
#pragma unroll
      for (int ni = 0; ni < 4; ni++) {
        unsigned int code = (cd[r] >> (8 * ni)) & 255u;
        float wsel = code == 0u ? w0 : (code == 1u ? w1 : (code == 2u ? w2 : 0.f));
        float p = exp2f(s[ni][r] * C2) * wsel;
        unsigned short pb = f2bf(p);
        psum += bf2f(pb);   // l sums exactly what PV uses
        Pl[w][prow * 64 + ((16 * ni + fr) ^ ((prow & 7) * 8))] = pb;
      }
      lacc[r] += psum;
    }
    // PV
#pragma unroll
    for (int ks = 0; ks < 2; ks++) {
      s16x8 pa = *(const s16x8*)&Pl[w][fr * 64 + ((ks * 32 + fs * 8) ^ ((fr & 7) * 8))];
#pragma unroll
      for (int dn = 0; dn < 4; dn++) {
        int row = 16 * dn + fr;
        s16x8 vf = *(const s16x8*)&Vt[row * 64 + ((ks * 32 + fs * 8) ^ ((row & 7) * 8))];
        o[dn] = __builtin_amdgcn_mfma_f32_16x16x32_bf16(pa, vf, o[dn], 0, 0, 0);
      }
    }
  }
  // reduce l across the 16 fr lanes (once, at the end)
#pragma unroll
  for (int r = 0; r < 4; r++) {
#pragma unroll
    for (int m = 1; m < 16; m <<= 1) lacc[r] += __shfl_xor(lacc[r], m);
  }
#pragma unroll
  for (int r = 0; r < 4; r++) {
    int row = qrow0 + fs * 4 + r;
#pragma unroll
    for (int dn = 0; dn < 4; dn++)
      po[((size_t)seg * NN + row) * EE + h * 64 + 16 * dn + fr] = o[dn][r];
    if (fr == 0) lpart[((size_t)seg * NN + row) * 8 + h] = lacc[r];
  }
}

// ---------------- combine split-KV partials: out = (sum o) / (sum l) ----------------
__global__ __launch_bounds__(256) void attn_combine(const float* __restrict__ po,
    const float* __restrict__ lpart, unsigned short* __restrict__ attnb) {
  int id = blockIdx.x * 256 + threadIdx.x;   // 2048*128
  int row = id >> 7;
  int col = (id & 127) * 4;
  int h = col >> 6;
  float4 o = {0.f, 0.f, 0.f, 0.f};
  float lsum = 0.f;
#pragma unroll
  for (int s = 0; s < NSEG; s++) {
    float4 p4 = *(const float4*)&po[((size_t)s * NN + row) * EE + col];
    o.x += p4.x; o.y += p4.y; o.z += p4.z; o.w += p4.w;
    lsum += lpart[((size_t)s * NN + row) * 8 + h];
  }
  float inv = 1.f / lsum;
  s16x4 ob;
  ob[0] = (short)f2bf(o.x * inv); ob[1] = (short)f2bf(o.y * inv);
  ob[2] = (short)f2bf(o.z * inv); ob[3] = (short)f2bf(o.w * inv);
  *(s16x4*)&attnb[(size_t)row * EE + col] = ob;
}

// ---------------- final logits + softmax (4 rows per block, fp32) ----------------
__global__ __launch_bounds__(256) void logits_kernel(const float* __restrict__ x,
    const float* __restrict__ cw, const float* __restrict__ cb,
    float* __restrict__ out) {
  int t = threadIdx.x;
  int wv = t >> 6, lane = t & 63;
  int row = blockIdx.x * 4 + wv;
  const float* xr = x + (size_t)row * EE;
  int c = lane >> 2, p = lane & 3;
  const float* w = cw + c * EE;
  float s = 0.f;
  for (int e = p * 128; e < p * 128 + 128; e++) s += xr[e] * w[e];
  s += __shfl_xor(s, 1);
  s += __shfl_xor(s, 2);
  __shared__ float lg[4][16];
  if (p == 0) lg[wv][c] = s + cb[c];
  __syncthreads();
  if (lane < 16) {
    float mx = -INFINITY;
#pragma unroll
    for (int k = 0; k < 16; k++) mx = fmaxf(mx, lg[wv][k]);
    float sum = 0.f;
#pragma unroll
    for (int k = 0; k < 16; k++) sum += __expf(lg[wv][k] - mx);
    out[(size_t)row * 16 + lane] = __expf(lg[wv][lane] - mx) / sum;
  }
}

// ---------------- driver ----------------
extern "C" void kernel_launch(void* const* d_in, const int* in_sizes, int n_in,
                              void* d_out, int out_size, void* d_ws, size_t ws_size,
                              hipStream_t stream) {
  const int* D = (const int*)d_in[0];
  const float* x = (const float*)d_in[1];
  const float* demb = (const float*)d_in[2];
  const float* dpw = (const float*)d_in[3];
  const float* dpb = (const float*)d_in[4];
  const float* ln1s = (const float*)d_in[5];
  const float* ln1b = (const float*)d_in[6];
  const float* ipw = (const float*)d_in[7];
  const float* ipb = (const float*)d_in[8];
  const float* ow = (const float*)d_in[9];
  const float* ob = (const float*)d_in[10];
  const float* ln2s = (const float*)d_in[11];
  const float* ln2b = (const float*)d_in[12];
  const float* f1w = (const float*)d_in[13];
  const float* f1b = (const float*)d_in[14];
  const float* f2w = (const float*)d_in[15];
  const float* f2b = (const float*)d_in[16];
  const float* cw = (const float*)d_in[17];
  const float* cb = (const float*)d_in[18];

  char* base = (char*)d_ws;
  unsigned int* codes = (unsigned int*)base;                        // @0,  4 MB
  float* xbuf = (float*)(base + (4u << 20));                        // @4,  4 MB
  unsigned short* qkv = (unsigned short*)(base + (8u << 20));       // @8,  6 MB
  unsigned short* xn = (unsigned short*)(base + (14u << 20));       // @14, 2 MB
  unsigned short* attnb = (unsigned short*)(base + (16u << 20));    // @16, 2 MB
  unsigned short* hbuf = (unsigned short*)(base + (18u << 20));     // @18, 4 MB
  unsigned short* ipw_bf = (unsigned short*)(base + (22u << 20));   // @22, 3 MB
  unsigned short* ow_bf = (unsigned short*)(base + (25u << 20));    // @25, 1 MB
  unsigned short* f1w_bf = (unsigned short*)(base + (26u << 20));   // @26, 2 MB
  unsigned short* f2w_bf = (unsigned short*)(base + (28u << 20));   // @28, 2 MB
  float* wtbl = (float*)(base + (30u << 20));                       // @30, tiny
  float* po = (float*)(base + (31u << 20));                         // @31, 16 MB
  float* lpart = (float*)(base + (47u << 20));                      // @47, 256 KB

  cvt_bf4<<<(393216 + 255) / 256, 256, 0, stream>>>(ipw, ipw_bf, 393216);
  cvt_bf4<<<(131072 + 255) / 256, 256, 0, stream>>>(ow, ow_bf, 131072);
  cvt_bf4<<<(262144 + 255) / 256, 256, 0, stream>>>(f1w, f1w_bf, 262144);
  cvt_bf4<<<(262144 + 255) / 256, 256, 0, stream>>>(f2w, f2w_bf, 262144);
  wtbl_kernel<<<1, 64, 0, stream>>>(demb, dpw, dpb, wtbl);
  mask_pack<<<4096, 256, 0, stream>>>(D, codes);
  hipMemcpyAsync(xbuf, x, (size_t)NN * EE * sizeof(float), hipMemcpyDeviceToDevice, stream);

  for (int l = 0; l < 2; l++) {
    ln_kernel<<<NN, 256, 0, stream>>>(xbuf, ln1s + l * EE, ln1b + l * EE, xn);
    gemm_bf<0, 0, 1><<<dim3(24, 16), 256, 0, stream>>>(
        xn, ipw_bf + (size_t)l * 786432, ipb + l * 1536, nullptr, qkv, NN, 1536, 512);
    attn_mfma<<<dim3(32, HH, NSEG), 256, 0, stream>>>(qkv, codes, wtbl, po, lpart);
    attn_combine<<<1024, 256, 0, stream>>>(po, lpart, attnb);
    gemm_bf<0, 1, 0><<<dim3(8, 16), 256, 0, stream>>>(
        attnb, ow_bf + (size_t)l * 262144, ob + l * EE, xbuf, xbuf, NN, 512, 512);
    ln_kernel<<<NN, 256, 0, stream>>>(xbuf, ln2s + l * EE, ln2b + l * EE, xn);
    gemm_bf<1, 0, 1><<<dim3(16, 16), 256, 0, stream>>>(
        xn, f1w_bf + (size_t)l * 524288, f1b + l * 1024, nullptr, hbuf, NN, 1024, 512);
    gemm_bf<0, 1, 0><<<dim3(8, 16), 256, 0, stream>>>(
        hbuf, f2w_bf + (size_t)l * 524288, f2b + l * EE, xbuf, xbuf, NN, 512, 1024);
  }
  logits_kernel<<<NN / 4, 256, 0, stream>>>(xbuf, cw, cb, (float*)d_out);
}

// Round 8
// 316.015 us; speedup vs baseline: 3.8545x; 1.0264x over previous
//
#include <hip/hip_runtime.h>
#include <cstddef>
#include <cstdint>

#define NN 2048
#define EE 512
#define HH 8
#define QKVF 1536
#define NSEG 4

typedef __attribute__((ext_vector_type(4))) float f32x4;
typedef __attribute__((ext_vector_type(8))) short s16x8;
typedef __attribute__((ext_vector_type(4))) short s16x4;

static __device__ __forceinline__ unsigned short f2bf(float x) {
  union { float f; unsigned int u; } c; c.f = x;
  unsigned int r = (c.u + 0x7FFFu + ((c.u >> 16) & 1u)) >> 16;
  return (unsigned short)r;
}
static __device__ __forceinline__ float bf2f(unsigned short b) {
  union { unsigned int u; float f; } c; c.u = ((unsigned int)b) << 16;
  return c.f;
}

#define GLL16(gp, lp) __builtin_amdgcn_global_load_lds( \
    (const __attribute__((address_space(1))) void*)(gp), \
    (__attribute__((address_space(3))) void*)(lp), 16, 0, 0)

// ---------------- all weights fp32 -> bf16, one dispatch ----------------
__global__ __launch_bounds__(256) void cvt_all(
    const float* __restrict__ s0, const float* __restrict__ s1,
    const float* __restrict__ s2, const float* __restrict__ s3,
    unsigned short* __restrict__ d0, unsigned short* __restrict__ d1,
    unsigned short* __restrict__ d2, unsigned short* __restrict__ d3,
    int n0, int n1, int n2, int n3) {
  int j = blockIdx.x * 256 + threadIdx.x;
  const float* s; unsigned short* d;
  if (j < n0) { s = s0; d = d0; }
  else {
    j -= n0;
    if (j < n1) { s = s1; d = d1; }
    else {
      j -= n1;
      if (j < n2) { s = s2; d = d2; }
      else { j -= n2; if (j >= n3) return; s = s3; d = d3; }
    }
  }
  float4 v = ((const float4*)s)[j];
  s16x4 o;
  o[0] = (short)f2bf(v.x); o[1] = (short)f2bf(v.y);
  o[2] = (short)f2bf(v.z); o[3] = (short)f2bf(v.w);
  ((s16x4*)d)[j] = o;
}

// ---------------- packed distance codes: u32 = codes for kv {c,c+16,c+32,c+48} ---
__global__ __launch_bounds__(256) void mask_pack(const int* __restrict__ D,
    unsigned int* __restrict__ codes) {
  int id = blockIdx.x * 256 + threadIdx.x;  // 2048*512 total
  int row = id >> 9;
  int u = id & 511;
  int ch = u >> 4, col = u & 15;
  int base = ch * 64 + col;
  unsigned int pk = 0;
#pragma unroll
  for (int i = 0; i < 4; i++) {
    int d = D[(size_t)row * NN + base + 16 * i];
    unsigned int c = (d <= 2) ? (unsigned int)d : 3u;
    pk |= c << (8 * i);
  }
  codes[id] = pk;
}

// ---------------- layernorm fp32 in -> bf16 out ----------------
__global__ __launch_bounds__(256) void ln_kernel(const float* __restrict__ x,
    const float* __restrict__ scale, const float* __restrict__ bias,
    unsigned short* __restrict__ out) {
  int row = blockIdx.x;
  int t = threadIdx.x;
  const float* xr = x + (size_t)row * EE;
  float a = xr[t], b = xr[t + 256];
  float s = a + b, q = a * a + b * b;
#pragma unroll
  for (int m = 1; m < 64; m <<= 1) {
    s += __shfl_xor(s, m);
    q += __shfl_xor(q, m);
  }
  __shared__ float ps[4], pq[4];
  int w = t >> 6;
  if ((t & 63) == 0) { ps[w] = s; pq[w] = q; }
  __syncthreads();
  s = ps[0] + ps[1] + ps[2] + ps[3];
  q = pq[0] + pq[1] + pq[2] + pq[3];
  float mu = s * (1.f / EE);
  float var = q * (1.f / EE) - mu * mu;
  float r = rsqrtf(var + 1e-5f);
  unsigned short* orow = out + (size_t)row * EE;
  orow[t] = f2bf((a - mu) * r * scale[t] + bias[t]);
  orow[t + 256] = f2bf((b - mu) * r * scale[t + 256] + bias[t + 256]);
}

// ------- bf16 MFMA GEMM, 64x64 tile, 2-phase dbuf: C = A.B^T + bias -------
template <int RELU, int RES, int OBF>
__global__ __launch_bounds__(256) void gemm_bf(
    const unsigned short* __restrict__ A, const unsigned short* __restrict__ B,
    const float* __restrict__ bias, const float* __restrict__ R,
    void* __restrict__ Cout, int M, int F, int K) {
  __shared__ __attribute__((aligned(16))) unsigned short Al[2][64 * 64];  // 2x8 KB
  __shared__ __attribute__((aligned(16))) unsigned short Bl[2][64 * 64];  // 2x8 KB
  const int t = threadIdx.x;
  const int w = t >> 6, l = t & 63;
  const int fr = l & 15, fs = l >> 4;
  const int bm = blockIdx.y * 64, bf = blockIdx.x * 64;
  const int srow = l >> 3, slot = l & 7;
  const int nk = K >> 6;

  f32x4 acc[4];
  f32x4 zero = {0.f, 0.f, 0.f, 0.f};
#pragma unroll
  for (int j = 0; j < 4; j++) acc[j] = zero;

  // stage K-tile kt into buffer bsel (async GLL16; wave-uniform LDS dest)
  auto stage = [&](int kt, int bsel) {
    int k0 = kt * 64;
#pragma unroll
    for (int rnd = 0; rnd < 2; rnd++) {
      int rowblk = w * 2 + rnd;              // 0..7, 8 rows each
      int row = rowblk * 8 + srow;           // 0..63
      int koff = (slot * 8) ^ ((row & 7) * 8);
      GLL16(A + (size_t)(bm + row) * K + k0 + koff, &Al[bsel][rowblk * 512]);
      GLL16(B + (size_t)(bf + row) * K + k0 + koff, &Bl[bsel][rowblk * 512]);
    }
  };

  stage(0, 0);
  __syncthreads();   // vmcnt(0) drain + barrier: buf0 ready
  for (int kt = 0; kt < nk; kt++) {
    const int cur = kt & 1;
    if (kt + 1 < nk) stage(kt + 1, cur ^ 1);   // flies under compute
    s16x8 af[2], bg[4][2];
    const int arow = w * 16 + fr;
#pragma unroll
    for (int ks = 0; ks < 2; ks++)
      af[ks] = *(const s16x8*)&Al[cur][arow * 64 + ((ks * 32 + fs * 8) ^ ((arow & 7) * 8))];
#pragma unroll
    for (int ni = 0; ni < 4; ni++)
#pragma unroll
      for (int ks = 0; ks < 2; ks++) {
        int row = 16 * ni + fr;
        bg[ni][ks] = *(const s16x8*)&Bl[cur][row * 64 + ((ks * 32 + fs * 8) ^ ((row & 7) * 8))];
      }
#pragma unroll
    for (int ni = 0; ni < 4; ni++)
#pragma unroll
      for (int ks = 0; ks < 2; ks++)
        acc[ni] = __builtin_amdgcn_mfma_f32_16x16x32_bf16(af[ks], bg[ni][ks], acc[ni], 0, 0, 0);
    __syncthreads();   // drains next-stage vmcnt(0); all waves done with buf[cur]
  }

#pragma unroll
  for (int ni = 0; ni < 4; ni++) {
    int gcol = bf + 16 * ni + fr;
    float bb = bias[gcol];
#pragma unroll
    for (int r = 0; r < 4; r++) {
      int grow = bm + w * 16 + fs * 4 + r;
      float v = acc[ni][r] + bb;
      if (RELU) v = fmaxf(v, 0.f);
      if (RES) v += R[(size_t)grow * F + gcol];
      if (OBF) ((unsigned short*)Cout)[(size_t)grow * F + gcol] = f2bf(v);
      else ((float*)Cout)[(size_t)grow * F + gcol] = v;
    }
  }
}

// -------- MFMA flash attention, split-KV: 64 q x 1 head x 512 kv per block ------
__global__ __launch_bounds__(256) void attn_mfma(
    const unsigned short* __restrict__ qkv, const unsigned int* __restrict__ codes,
    const float* __restrict__ demb, const float* __restrict__ dpw,
    const float* __restrict__ dpb, float* __restrict__ po, float* __restrict__ lpart) {
  __shared__ __attribute__((aligned(16))) unsigned short Kl[64 * 64];
  __shared__ __attribute__((aligned(16))) unsigned short Vt[64 * 64];
  __shared__ __attribute__((aligned(16))) unsigned short Pl[4][16 * 64];
  const int t = threadIdx.x;
  const int w = t >> 6, l = t & 63;
  const int fr = l & 15, fs = l >> 4;
  const int h = blockIdx.y;
  const int seg = blockIdx.z;
  const int qrow0 = blockIdx.x * 64 + w * 16;
  const int kvbase = seg * (NN / NSEG);
  const float C2 = 0.18033688011112042f;  // 0.125 * log2(e)

  // bias weight table (uniform per block; 3 dot-8 + 3 exp, negligible)
  float w0, w1, w2;
  {
    float s0 = 0.f, s1 = 0.f, s2 = 0.f;
#pragma unroll
    for (int e = 0; e < 8; e++) {
      float pw = dpw[e];
      s0 += demb[e] * pw; s1 += demb[8 + e] * pw; s2 += demb[16 + e] * pw;
    }
    float b = dpb[0];
    w0 = __expf(s0 + b); w1 = __expf(s1 + b); w2 = __expf(s2 + b);
  }

  s16x8 qf[2];
#pragma unroll
  for (int ks = 0; ks < 2; ks++)
    qf[ks] = *(const s16x8*)&qkv[(size_t)(qrow0 + fr) * QKVF + h * 64 + ks * 32 + fs * 8];

  f32x4 o[4];
  float lacc[4];
  f32x4 zero = {0.f, 0.f, 0.f, 0.f};
#pragma unroll
  for (int i = 0; i < 4; i++) { o[i] = zero; lacc[i] = 0.f; }

  const int krow = t >> 2, kc = (t & 3) * 16;
  const int vkv = (t & 15) * 4, vd = (t >> 4) * 4;
  const unsigned short* kbase = qkv + EE + h * 64;
  const unsigned short* vbase = qkv + 2 * EE + h * 64;
  s16x8 kreg[2];
  s16x4 vreg[4];
#pragma unroll
  for (int i = 0; i < 2; i++)
    kreg[i] = *(const s16x8*)&kbase[(size_t)(kvbase + krow) * QKVF + kc + i * 8];
#pragma unroll
  for (int i = 0; i < 4; i++)
    vreg[i] = *(const s16x4*)&vbase[(size_t)(kvbase + vkv + i) * QKVF + vd];

  for (int ch = 0; ch < NN / NSEG / 64; ch++) {
    __syncthreads();   // previous chunk's LDS reads done
#pragma unroll
    for (int i = 0; i < 2; i++)
      *(s16x8*)&Kl[krow * 64 + ((kc + i * 8) ^ ((krow & 7) * 8))] = kreg[i];
#pragma unroll
    for (int dj = 0; dj < 4; dj++) {
      int d = vd + dj;
      s16x4 pk;
      pk[0] = vreg[0][dj]; pk[1] = vreg[1][dj]; pk[2] = vreg[2][dj]; pk[3] = vreg[3][dj];
      *(s16x4*)&Vt[d * 64 + (vkv ^ ((d & 7) * 8))] = pk;
    }
    __syncthreads();   // staging visible
    if (ch + 1 < NN / NSEG / 64) {
      int kv0 = kvbase + (ch + 1) * 64;
#pragma unroll
      for (int i = 0; i < 2; i++)
        kreg[i] = *(const s16x8*)&kbase[(size_t)(kv0 + krow) * QKVF + kc + i * 8];
#pragma unroll
      for (int i = 0; i < 4; i++)
        vreg[i] = *(const s16x4*)&vbase[(size_t)(kv0 + vkv + i) * QKVF + vd];
    }
    int gc = kvbase / 64 + ch;
    unsigned int cd[4];
#pragma unroll
    for (int r = 0; r < 4; r++)
      cd[r] = codes[(size_t)(qrow0 + fs * 4 + r) * (NN / 4) + gc * 16 + fr];

    // QK^T
    f32x4 s[4];
#pragma unroll
    for (int ni = 0; ni < 4; ni++) s[ni] = zero;
    __builtin_amdgcn_s_setprio(1);
#pragma unroll
    for (int ni = 0; ni < 4; ni++) {
      int row = 16 * ni + fr;
#pragma unroll
      for (int ks = 0; ks < 2; ks++) {
        s16x8 kf = *(const s16x8*)&Kl[row * 64 + ((ks * 32 + fs * 8) ^ ((row & 7) * 8))];
        s[ni] = __builtin_amdgcn_mfma_f32_16x16x32_bf16(qf[ks], kf, s[ni], 0, 0, 0);
      }
    }
    __builtin_amdgcn_s_setprio(0);
    // softmax numerator, fixed reference point (m = 0): p = 2^(s*C2) * w[code]
#pragma unroll
    for (int r = 0; r < 4; r++) {
      int prow = fs * 4 + r;
      float psum = 0.f;
#pragma unroll
      for (int ni = 0; ni < 4; ni++) {
        unsigned int code = (cd[r] >> (8 * ni)) & 255u;
        float wsel = code == 0u ? w0 : (code == 1u ? w1 : (code == 2u ? w2 : 0.f));
        float p = exp2f(s[ni][r] * C2) * wsel;
        unsigned short pb = f2bf(p);
        psum += bf2f(pb);   // l sums exactly what PV uses
        Pl[w][prow * 64 + ((16 * ni + fr) ^ ((prow & 7) * 8))] = pb;
      }
      lacc[r] += psum;
    }
    // PV
    __builtin_amdgcn_s_setprio(1);
#pragma unroll
    for (int ks = 0; ks < 2; ks++) {
      s16x8 pa = *(const s16x8*)&Pl[w][fr * 64 + ((ks * 32 + fs * 8) ^ ((fr & 7) * 8))];
#pragma unroll
      for (int dn = 0; dn < 4; dn++) {
        int row = 16 * dn + fr;
        s16x8 vf = *(const s16x8*)&Vt[row * 64 + ((ks * 32 + fs * 8) ^ ((row & 7) * 8))];
        o[dn] = __builtin_amdgcn_mfma_f32_16x16x32_bf16(pa, vf, o[dn], 0, 0, 0);
      }
    }
    __builtin_amdgcn_s_setprio(0);
  }
  // reduce l across the 16 fr lanes (once, at the end)
#pragma unroll
  for (int r = 0; r < 4; r++) {
#pragma unroll
    for (int m = 1; m < 16; m <<= 1) lacc[r] += __shfl_xor(lacc[r], m);
  }
#pragma unroll
  for (int r = 0; r < 4; r++) {
    int row = qrow0 + fs * 4 + r;
#pragma unroll
    for (int dn = 0; dn < 4; dn++)
      po[((size_t)seg * NN + row) * EE + h * 64 + 16 * dn + fr] = o[dn][r];
    if (fr == 0) lpart[((size_t)seg * NN + row) * 8 + h] = lacc[r];
  }
}

// ---------------- combine split-KV partials: out = (sum o) / (sum l) ----------------
__global__ __launch_bounds__(256) void attn_combine(const float* __restrict__ po,
    const float* __restrict__ lpart, unsigned short* __restrict__ attnb) {
  int id = blockIdx.x * 256 + threadIdx.x;   // 2048*128
  int row = id >> 7;
  int col = (id & 127) * 4;
  int h = col >> 6;
  float4 o = {0.f, 0.f, 0.f, 0.f};
  float lsum = 0.f;
#pragma unroll
  for (int s = 0; s < NSEG; s++) {
    float4 p4 = *(const float4*)&po[((size_t)s * NN + row) * EE + col];
    o.x += p4.x; o.y += p4.y; o.z += p4.z; o.w += p4.w;
    lsum += lpart[((size_t)s * NN + row) * 8 + h];
  }
  float inv = 1.f / lsum;
  s16x4 ob;
  ob[0] = (short)f2bf(o.x * inv); ob[1] = (short)f2bf(o.y * inv);
  ob[2] = (short)f2bf(o.z * inv); ob[3] = (short)f2bf(o.w * inv);
  *(s16x4*)&attnb[(size_t)row * EE + col] = ob;
}

// ---------------- final logits + softmax (4 rows per block, fp32) ----------------
__global__ __launch_bounds__(256) void logits_kernel(const float* __restrict__ x,
    const float* __restrict__ cw, const float* __restrict__ cb,
    float* __restrict__ out) {
  int t = threadIdx.x;
  int wv = t >> 6, lane = t & 63;
  int row = blockIdx.x * 4 + wv;
  const float* xr = x + (size_t)row * EE;
  int c = lane >> 2, p = lane & 3;
  const float* w = cw + c * EE;
  float s = 0.f;
  for (int e = p * 128; e < p * 128 + 128; e++) s += xr[e] * w[e];
  s += __shfl_xor(s, 1);
  s += __shfl_xor(s, 2);
  __shared__ float lg[4][16];
  if (p == 0) lg[wv][c] = s + cb[c];
  __syncthreads();
  if (lane < 16) {
    float mx = -INFINITY;
#pragma unroll
    for (int k = 0; k < 16; k++) mx = fmaxf(mx, lg[wv][k]);
    float sum = 0.f;
#pragma unroll
    for (int k = 0; k < 16; k++) sum += __expf(lg[wv][k] - mx);
    out[(size_t)row * 16 + lane] = __expf(lg[wv][lane] - mx) / sum;
  }
}

// ---------------- driver ----------------
extern "C" void kernel_launch(void* const* d_in, const int* in_sizes, int n_in,
                              void* d_out, int out_size, void* d_ws, size_t ws_size,
                              hipStream_t stream) {
  const int* D = (const int*)d_in[0];
  const float* x = (const float*)d_in[1];
  const float* demb = (const float*)d_in[2];
  const float* dpw = (const float*)d_in[3];
  const float* dpb = (const float*)d_in[4];
  const float* ln1s = (const float*)d_in[5];
  const float* ln1b = (const float*)d_in[6];
  const float* ipw = (const float*)d_in[7];
  const float* ipb = (const float*)d_in[8];
  const float* ow = (const float*)d_in[9];
  const float* ob = (const float*)d_in[10];
  const float* ln2s = (const float*)d_in[11];
  const float* ln2b = (const float*)d_in[12];
  const float* f1w = (const float*)d_in[13];
  const float* f1b = (const float*)d_in[14];
  const float* f2w = (const float*)d_in[15];
  const float* f2b = (const float*)d_in[16];
  const float* cw = (const float*)d_in[17];
  const float* cb = (const float*)d_in[18];

  char* base = (char*)d_ws;
  unsigned int* codes = (unsigned int*)base;                        // @0,  4 MB
  float* xbuf = (float*)(base + (4u << 20));                        // @4,  4 MB
  unsigned short* qkv = (unsigned short*)(base + (8u << 20));       // @8,  6 MB
  unsigned short* xn = (unsigned short*)(base + (14u << 20));       // @14, 2 MB
  unsigned short* attnb = (unsigned short*)(base + (16u << 20));    // @16, 2 MB
  unsigned short* hbuf = (unsigned short*)(base + (18u << 20));     // @18, 4 MB
  unsigned short* ipw_bf = (unsigned short*)(base + (22u << 20));   // @22, 3 MB
  unsigned short* ow_bf = (unsigned short*)(base + (25u << 20));    // @25, 1 MB
  unsigned short* f1w_bf = (unsigned short*)(base + (26u << 20));   // @26, 2 MB
  unsigned short* f2w_bf = (unsigned short*)(base + (28u << 20));   // @28, 2 MB
  float* po = (float*)(base + (31u << 20));                         // @31, 16 MB
  float* lpart = (float*)(base + (47u << 20));                      // @47, 256 KB

  cvt_all<<<4096, 256, 0, stream>>>(ipw, ow, f1w, f2w,
      ipw_bf, ow_bf, f1w_bf, f2w_bf, 393216, 131072, 262144, 262144);
  mask_pack<<<4096, 256, 0, stream>>>(D, codes);

  for (int l = 0; l < 2; l++) {
    const float* xin = (l == 0) ? x : xbuf;   // layer-0 reads input directly
    ln_kernel<<<NN, 256, 0, stream>>>(xin, ln1s + l * EE, ln1b + l * EE, xn);
    gemm_bf<0, 0, 1><<<dim3(24, 32), 256, 0, stream>>>(
        xn, ipw_bf + (size_t)l * 786432, ipb + l * 1536, nullptr, qkv, NN, 1536, 512);
    attn_mfma<<<dim3(32, HH, NSEG), 256, 0, stream>>>(qkv, codes, demb, dpw, dpb, po, lpart);
    attn_combine<<<1024, 256, 0, stream>>>(po, lpart, attnb);
    gemm_bf<0, 1, 0><<<dim3(8, 32), 256, 0, stream>>>(
        attnb, ow_bf + (size_t)l * 262144, ob + l * EE, xin, xbuf, NN, 512, 512);
    ln_kernel<<<NN, 256, 0, stream>>>(xbuf, ln2s + l * EE, ln2b + l * EE, xn);
    gemm_bf<1, 0, 1><<<dim3(16, 32), 256, 0, stream>>>(
        xn, f1w_bf + (size_t)l * 524288, f1b + l * 1024, nullptr, hbuf, NN, 1024, 512);
    gemm_bf<0, 1, 0><<<dim3(8, 32), 256, 0, stream>>>(
        hbuf, f2w_bf + (size_t)l * 524288, f2b + l * EE, xbuf, xbuf, NN, 512, 1024);
  }
  logits_kernel<<<NN / 4, 256, 0, stream>>>(xbuf, cw, cb, (float*)d_out);
}

// Round 10
// 300.281 us; speedup vs baseline: 4.0564x; 1.0524x over previous
//
#include <hip/hip_runtime.h>
#include <cstddef>
#include <cstdint>

#define NN 2048
#define EE 512
#define HH 8
#define QKVF 1536
#define NSEG 8

typedef __attribute__((ext_vector_type(4))) float f32x4;
typedef __attribute__((ext_vector_type(8))) short s16x8;
typedef __attribute__((ext_vector_type(4))) short s16x4;

static __device__ __forceinline__ unsigned short f2bf(float x) {
  union { float f; unsigned int u; } c; c.f = x;
  unsigned int r = (c.u + 0x7FFFu + ((c.u >> 16) & 1u)) >> 16;
  return (unsigned short)r;
}

#define GLL16(gp, lp) __builtin_amdgcn_global_load_lds( \
    (const __attribute__((address_space(1))) void*)(gp), \
    (__attribute__((address_space(3))) void*)(lp), 16, 0, 0)

// ------- prep: weight cvt (blocks 0..4095) + fp32 mask-weight table (4096..8191) ----
__global__ __launch_bounds__(256) void prep(
    const float* __restrict__ s0, const float* __restrict__ s1,
    const float* __restrict__ s2, const float* __restrict__ s3,
    unsigned short* __restrict__ d0, unsigned short* __restrict__ d1,
    unsigned short* __restrict__ d2, unsigned short* __restrict__ d3,
    const int* __restrict__ D, const float* __restrict__ demb,
    const float* __restrict__ dpw, const float* __restrict__ dpb,
    float* __restrict__ wpk4) {
  int b = blockIdx.x;
  if (b < 4096) {
    int j = b * 256 + threadIdx.x;   // 0..1048575 == 393216+131072+262144+262144
    const float* s; unsigned short* d;
    if (j < 393216) { s = s0; d = d0; }
    else {
      j -= 393216;
      if (j < 131072) { s = s1; d = d1; }
      else {
        j -= 131072;
        if (j < 262144) { s = s2; d = d2; }
        else { j -= 262144; s = s3; d = d3; }
      }
    }
    float4 v = ((const float4*)s)[j];
    s16x4 o;
    o[0] = (short)f2bf(v.x); o[1] = (short)f2bf(v.y);
    o[2] = (short)f2bf(v.z); o[3] = (short)f2bf(v.w);
    ((s16x4*)d)[j] = o;
  } else {
    int e = (b - 4096) * 256 + threadIdx.x;  // 2048*512 float4 entries
    float ws0 = 0.f, ws1 = 0.f, ws2 = 0.f;
#pragma unroll
    for (int k = 0; k < 8; k++) {
      float pw = dpw[k];
      ws0 += demb[k] * pw; ws1 += demb[8 + k] * pw; ws2 += demb[16 + k] * pw;
    }
    float bb = dpb[0];
    float w0 = __expf(ws0 + bb), w1 = __expf(ws1 + bb), w2 = __expf(ws2 + bb);
    int row = e >> 9;
    int u = e & 511;
    int base = (u >> 4) * 64 + (u & 15);
    f32x4 wv;
#pragma unroll
    for (int i = 0; i < 4; i++) {
      int d = D[(size_t)row * NN + base + 16 * i];
      wv[i] = (d == 0) ? w0 : (d == 1) ? w1 : (d == 2) ? w2 : 0.f;
    }
    ((f32x4*)wpk4)[e] = wv;
  }
}

// ---------------- layernorm fp32 in -> bf16 out ----------------
__global__ __launch_bounds__(256) void ln_kernel(const float* __restrict__ x,
    const float* __restrict__ scale, const float* __restrict__ bias,
    unsigned short* __restrict__ out) {
  int row = blockIdx.x;
  int t = threadIdx.x;
  const float* xr = x + (size_t)row * EE;
  float a = xr[t], b = xr[t + 256];
  float s = a + b, q = a * a + b * b;
#pragma unroll
  for (int m = 1; m < 64; m <<= 1) {
    s += __shfl_xor(s, m);
    q += __shfl_xor(q, m);
  }
  __shared__ float ps[4], pq[4];
  int w = t >> 6;
  if ((t & 63) == 0) { ps[w] = s; pq[w] = q; }
  __syncthreads();
  s = ps[0] + ps[1] + ps[2] + ps[3];
  q = pq[0] + pq[1] + pq[2] + pq[3];
  float mu = s * (1.f / EE);
  float var = q * (1.f / EE) - mu * mu;
  float r = rsqrtf(var + 1e-5f);
  unsigned short* orow = out + (size_t)row * EE;
  orow[t] = f2bf((a - mu) * r * scale[t] + bias[t]);
  orow[t + 256] = f2bf((b - mu) * r * scale[t + 256] + bias[t + 256]);
}

// ------- bf16 MFMA GEMM, 64x64 tile, 2-phase dbuf: C = A.B^T + bias -------
template <int RELU, int RES, int OBF>
__global__ __launch_bounds__(256) void gemm_bf(
    const unsigned short* __restrict__ A, const unsigned short* __restrict__ B,
    const float* __restrict__ bias, const float* __restrict__ R,
    void* __restrict__ Cout, int M, int F, int K) {
  __shared__ __attribute__((aligned(16))) unsigned short Al[2][64 * 64];
  __shared__ __attribute__((aligned(16))) unsigned short Bl[2][64 * 64];
  const int t = threadIdx.x;
  const int w = t >> 6, l = t & 63;
  const int fr = l & 15, fs = l >> 4;
  const int bm = blockIdx.y * 64, bf = blockIdx.x * 64;
  const int srow = l >> 3, slot = l & 7;
  const int nk = K >> 6;

  f32x4 acc[4];
  f32x4 zero = {0.f, 0.f, 0.f, 0.f};
#pragma unroll
  for (int j = 0; j < 4; j++) acc[j] = zero;

  auto stage = [&](int kt, int bsel) {
    int k0 = kt * 64;
#pragma unroll
    for (int rnd = 0; rnd < 2; rnd++) {
      int rowblk = w * 2 + rnd;
      int row = rowblk * 8 + srow;
      int koff = (slot * 8) ^ ((row & 7) * 8);
      GLL16(A + (size_t)(bm + row) * K + k0 + koff, &Al[bsel][rowblk * 512]);
      GLL16(B + (size_t)(bf + row) * K + k0 + koff, &Bl[bsel][rowblk * 512]);
    }
  };

  stage(0, 0);
  __syncthreads();
  for (int kt = 0; kt < nk; kt++) {
    const int cur = kt & 1;
    if (kt + 1 < nk) stage(kt + 1, cur ^ 1);
    s16x8 af[2], bg[4][2];
    const int arow = w * 16 + fr;
#pragma unroll
    for (int ks = 0; ks < 2; ks++)
      af[ks] = *(const s16x8*)&Al[cur][arow * 64 + ((ks * 32 + fs * 8) ^ ((arow & 7) * 8))];
#pragma unroll
    for (int ni = 0; ni < 4; ni++)
#pragma unroll
      for (int ks = 0; ks < 2; ks++) {
        int row = 16 * ni + fr;
        bg[ni][ks] = *(const s16x8*)&Bl[cur][row * 64 + ((ks * 32 + fs * 8) ^ ((row & 7) * 8))];
      }
#pragma unroll
    for (int ni = 0; ni < 4; ni++)
#pragma unroll
      for (int ks = 0; ks < 2; ks++)
        acc[ni] = __builtin_amdgcn_mfma_f32_16x16x32_bf16(af[ks], bg[ni][ks], acc[ni], 0, 0, 0);
    __syncthreads();
  }

#pragma unroll
  for (int ni = 0; ni < 4; ni++) {
    int gcol = bf + 16 * ni + fr;
    float bb = bias[gcol];
#pragma unroll
    for (int r = 0; r < 4; r++) {
      int grow = bm + w * 16 + fs * 4 + r;
      float v = acc[ni][r] + bb;
      if (RELU) v = fmaxf(v, 0.f);
      if (RES) v += R[(size_t)grow * F + gcol];
      if (OBF) ((unsigned short*)Cout)[(size_t)grow * F + gcol] = f2bf(v);
      else ((float*)Cout)[(size_t)grow * F + gcol] = v;
    }
  }
}

// -------- MFMA flash attention, split-KV: 64 q x 1 head x 256 kv per block ------
// l computed via MFMA against a ones-row appended to Vt (row 64).
__global__ __launch_bounds__(256) void attn_mfma(
    const unsigned short* __restrict__ qkv, const float* __restrict__ wpk4,
    float* __restrict__ po, float* __restrict__ lpart) {
  __shared__ __attribute__((aligned(16))) unsigned short Kl[64 * 64];   // 8 KB
  __shared__ __attribute__((aligned(16))) unsigned short Vt[66 * 64];   // 8.25 KB (+ones row)
  __shared__ __attribute__((aligned(16))) unsigned short Pl[4][16 * 64];// 8 KB
  const int t = threadIdx.x;
  const int w = t >> 6, l = t & 63;
  const int fr = l & 15, fs = l >> 4;
  const int h = blockIdx.y;
  const int seg = blockIdx.z;
  const int qrow0 = blockIdx.x * 64 + w * 16;
  const int kvbase = seg * (NN / NSEG);
  const float C2 = 0.18033688011112042f;  // 0.125 * log2(e)

  if (t < 64) Vt[64 * 64 + t] = 0x3F80;   // ones row (bf16 1.0); rows 65+ junk, cols discarded

  s16x8 qf[2];
#pragma unroll
  for (int ks = 0; ks < 2; ks++)
    qf[ks] = *(const s16x8*)&qkv[(size_t)(qrow0 + fr) * QKVF + h * 64 + ks * 32 + fs * 8];

  f32x4 o[4], o4;
  f32x4 zero = {0.f, 0.f, 0.f, 0.f};
#pragma unroll
  for (int i = 0; i < 4; i++) o[i] = zero;
  o4 = zero;

  const int krow = t >> 2, kc = (t & 3) * 16;
  const int vkv = (t & 15) * 4, vd = (t >> 4) * 4;
  const unsigned short* kbase = qkv + EE + h * 64;
  const unsigned short* vbase = qkv + 2 * EE + h * 64;
  s16x8 kreg[2];
  s16x4 vreg[4];
#pragma unroll
  for (int i = 0; i < 2; i++)
    kreg[i] = *(const s16x8*)&kbase[(size_t)(kvbase + krow) * QKVF + kc + i * 8];
#pragma unroll
  for (int i = 0; i < 4; i++)
    vreg[i] = *(const s16x4*)&vbase[(size_t)(kvbase + vkv + i) * QKVF + vd];

  for (int ch = 0; ch < NN / NSEG / 64; ch++) {
    __syncthreads();   // previous chunk's LDS reads done (also covers ones-row init)
#pragma unroll
    for (int i = 0; i < 2; i++)
      *(s16x8*)&Kl[krow * 64 + ((kc + i * 8) ^ ((krow & 7) * 8))] = kreg[i];
#pragma unroll
    for (int dj = 0; dj < 4; dj++) {
      int d = vd + dj;
      s16x4 pk;
      pk[0] = vreg[0][dj]; pk[1] = vreg[1][dj]; pk[2] = vreg[2][dj]; pk[3] = vreg[3][dj];
      *(s16x4*)&Vt[d * 64 + (vkv ^ ((d & 7) * 8))] = pk;
    }
    __syncthreads();   // staging visible
    if (ch + 1 < NN / NSEG / 64) {
      int kv0 = kvbase + (ch + 1) * 64;
#pragma unroll
      for (int i = 0; i < 2; i++)
        kreg[i] = *(const s16x8*)&kbase[(size_t)(kv0 + krow) * QKVF + kc + i * 8];
#pragma unroll
      for (int i = 0; i < 4; i++)
        vreg[i] = *(const s16x4*)&vbase[(size_t)(kv0 + vkv + i) * QKVF + vd];
    }
    int gc = kvbase / 64 + ch;

    // QK^T
    f32x4 s[4];
#pragma unroll
    for (int ni = 0; ni < 4; ni++) s[ni] = zero;
    __builtin_amdgcn_s_setprio(1);
#pragma unroll
    for (int ni = 0; ni < 4; ni++) {
      int row = 16 * ni + fr;
#pragma unroll
      for (int ks = 0; ks < 2; ks++) {
        s16x8 kf = *(const s16x8*)&Kl[row * 64 + ((ks * 32 + fs * 8) ^ ((row & 7) * 8))];
        s[ni] = __builtin_amdgcn_mfma_f32_16x16x32_bf16(qf[ks], kf, s[ni], 0, 0, 0);
      }
    }
    __builtin_amdgcn_s_setprio(0);
    // softmax numerator, fixed ref (m=0): p = 2^(s*C2) * w_ij; P stored bf16-truncated
#pragma unroll
    for (int r = 0; r < 4; r++) {
      int prow = fs * 4 + r;
      f32x4 wv = *(const f32x4*)&wpk4[((size_t)(qrow0 + prow) * 512 + gc * 16 + fr) * 4];
#pragma unroll
      for (int ni = 0; ni < 4; ni++) {
        union { float f; unsigned int u; } c;
        c.f = exp2f(s[ni][r] * C2) * wv[ni];
        Pl[w][prow * 64 + ((16 * ni + fr) ^ ((prow & 7) * 8))] =
            (unsigned short)(c.u >> 16);
      }
    }
    // PV (+ ones-row tile accumulates l into o4)
    __builtin_amdgcn_s_setprio(1);
#pragma unroll
    for (int ks = 0; ks < 2; ks++) {
      s16x8 pa = *(const s16x8*)&Pl[w][fr * 64 + ((ks * 32 + fs * 8) ^ ((fr & 7) * 8))];
#pragma unroll
      for (int dn = 0; dn < 4; dn++) {
        int row = 16 * dn + fr;
        s16x8 vf = *(const s16x8*)&Vt[row * 64 + ((ks * 32 + fs * 8) ^ ((row & 7) * 8))];
        o[dn] = __builtin_amdgcn_mfma_f32_16x16x32_bf16(pa, vf, o[dn], 0, 0, 0);
      }
      s16x8 vf4 = *(const s16x8*)&Vt[(64 + fr) * 64 + ((ks * 32 + fs * 8) ^ ((fr & 7) * 8))];
      o4 = __builtin_amdgcn_mfma_f32_16x16x32_bf16(pa, vf4, o4, 0, 0, 0);
    }
    __builtin_amdgcn_s_setprio(0);
  }
#pragma unroll
  for (int r = 0; r < 4; r++) {
    int row = qrow0 + fs * 4 + r;
#pragma unroll
    for (int dn = 0; dn < 4; dn++)
      po[((size_t)seg * NN + row) * EE + h * 64 + 16 * dn + fr] = o[dn][r];
    if (fr == 0) lpart[((size_t)seg * NN + row) * 8 + h] = o4[r];  // col 0 of ones-tile = l
  }
}

// ---------------- combine split-KV partials: out = (sum o) / (sum l) ----------------
__global__ __launch_bounds__(256) void attn_combine(const float* __restrict__ po,
    const float* __restrict__ lpart, unsigned short* __restrict__ attnb) {
  int id = blockIdx.x * 256 + threadIdx.x;   // 2048*128
  int row = id >> 7;
  int col = (id & 127) * 4;
  int h = col >> 6;
  float4 o = {0.f, 0.f, 0.f, 0.f};
  float lsum = 0.f;
#pragma unroll
  for (int s = 0; s < NSEG; s++) {
    float4 p4 = *(const float4*)&po[((size_t)s * NN + row) * EE + col];
    o.x += p4.x; o.y += p4.y; o.z += p4.z; o.w += p4.w;
    lsum += lpart[((size_t)s * NN + row) * 8 + h];
  }
  float inv = 1.f / lsum;
  s16x4 ob;
  ob[0] = (short)f2bf(o.x * inv); ob[1] = (short)f2bf(o.y * inv);
  ob[2] = (short)f2bf(o.z * inv); ob[3] = (short)f2bf(o.w * inv);
  *(s16x4*)&attnb[(size_t)row * EE + col] = ob;
}

// ---------------- final logits + softmax (4 rows per block, fp32) ----------------
__global__ __launch_bounds__(256) void logits_kernel(const float* __restrict__ x,
    const float* __restrict__ cw, const float* __restrict__ cb,
    float* __restrict__ out) {
  int t = threadIdx.x;
  int wv = t >> 6, lane = t & 63;
  int row = blockIdx.x * 4 + wv;
  const float* xr = x + (size_t)row * EE;
  int c = lane >> 2, p = lane & 3;
  const float* w = cw + c * EE;
  float s = 0.f;
  for (int e = p * 128; e < p * 128 + 128; e++) s += xr[e] * w[e];
  s += __shfl_xor(s, 1);
  s += __shfl_xor(s, 2);
  __shared__ float lg[4][16];
  if (p == 0) lg[wv][c] = s + cb[c];
  __syncthreads();
  if (lane < 16) {
    float mx = -INFINITY;
#pragma unroll
    for (int k = 0; k < 16; k++) mx = fmaxf(mx, lg[wv][k]);
    float sum = 0.f;
#pragma unroll
    for (int k = 0; k < 16; k++) sum += __expf(lg[wv][k] - mx);
    out[(size_t)row * 16 + lane] = __expf(lg[wv][lane] - mx) / sum;
  }
}

// ---------------- driver ----------------
extern "C" void kernel_launch(void* const* d_in, const int* in_sizes, int n_in,
                              void* d_out, int out_size, void* d_ws, size_t ws_size,
                              hipStream_t stream) {
  const int* D = (const int*)d_in[0];
  const float* x = (const float*)d_in[1];
  const float* demb = (const float*)d_in[2];
  const float* dpw = (const float*)d_in[3];
  const float* dpb = (const float*)d_in[4];
  const float* ln1s = (const float*)d_in[5];
  const float* ln1b = (const float*)d_in[6];
  const float* ipw = (const float*)d_in[7];
  const float* ipb = (const float*)d_in[8];
  const float* ow = (const float*)d_in[9];
  const float* ob = (const float*)d_in[10];
  const float* ln2s = (const float*)d_in[11];
  const float* ln2b = (const float*)d_in[12];
  const float* f1w = (const float*)d_in[13];
  const float* f1b = (const float*)d_in[14];
  const float* f2w = (const float*)d_in[15];
  const float* f2b = (const float*)d_in[16];
  const float* cw = (const float*)d_in[17];
  const float* cb = (const float*)d_in[18];

  char* base = (char*)d_ws;
  float* wpk4 = (float*)base;                                       // @0,  16 MB
  float* xbuf = (float*)(base + (16u << 20));                       // @16, 4 MB
  unsigned short* qkv = (unsigned short*)(base + (20u << 20));      // @20, 6 MB
  unsigned short* xn = (unsigned short*)(base + (26u << 20));       // @26, 2 MB
  unsigned short* attnb = (unsigned short*)(base + (28u << 20));    // @28, 2 MB
  unsigned short* hbuf = (unsigned short*)(base + (30u << 20));     // @30, 4 MB
  unsigned short* ipw_bf = (unsigned short*)(base + (34u << 20));   // @34, 3 MB
  unsigned short* ow_bf = (unsigned short*)(base + (37u << 20));    // @37, 1 MB
  unsigned short* f1w_bf = (unsigned short*)(base + (38u << 20));   // @38, 2 MB
  unsigned short* f2w_bf = (unsigned short*)(base + (40u << 20));   // @40, 2 MB
  float* po = (float*)(base + (42u << 20));                         // @42, 32 MB
  float* lpart = (float*)(base + (74u << 20));                      // @74, 512 KB

  prep<<<8192, 256, 0, stream>>>(ipw, ow, f1w, f2w,
      ipw_bf, ow_bf, f1w_bf, f2w_bf, D, demb, dpw, dpb, wpk4);

  for (int l = 0; l < 2; l++) {
    const float* xin = (l == 0) ? x : xbuf;
    ln_kernel<<<NN, 256, 0, stream>>>(xin, ln1s + l * EE, ln1b + l * EE, xn);
    gemm_bf<0, 0, 1><<<dim3(24, 32), 256, 0, stream>>>(
        xn, ipw_bf + (size_t)l * 786432, ipb + l * 1536, nullptr, qkv, NN, 1536, 512);
    attn_mfma<<<dim3(32, HH, NSEG), 256, 0, stream>>>(qkv, wpk4, po, lpart);
    attn_combine<<<1024, 256, 0, stream>>>(po, lpart, attnb);
    gemm_bf<0, 1, 0><<<dim3(8, 32), 256, 0, stream>>>(
        attnb, ow_bf + (size_t)l * 262144, ob + l * EE, xin, xbuf, NN, 512, 512);
    ln_kernel<<<NN, 256, 0, stream>>>(xbuf, ln2s + l * EE, ln2b + l * EE, xn);
    gemm_bf<1, 0, 1><<<dim3(16, 32), 256, 0, stream>>>(
        xn, f1w_bf + (size_t)l * 524288, f1b + l * 1024, nullptr, hbuf, NN, 1024, 512);
    gemm_bf<0, 1, 0><<<dim3(8, 32), 256, 0, stream>>>(
        hbuf, f2w_bf + (size_t)l * 524288, f2b + l * EE, xbuf, xbuf, NN, 512, 1024);
  }
  logits_kernel<<<NN / 4, 256, 0, stream>>>(xbuf, cw, cb, (float*)d_out);
}